// Round 6
// baseline (534.533 us; speedup 1.0000x reference)
//
#include <hip/hip_runtime.h>

#define H 128

typedef float v4f __attribute__((ext_vector_type(4)));
typedef short v8s __attribute__((ext_vector_type(8)));

// ---------------- bf16 helpers ----------------

__device__ inline unsigned short bf16_rne(float x) {
  unsigned u = __builtin_bit_cast(unsigned, x);
  unsigned r = u + 0x7FFF + ((u >> 16) & 1);
  return (unsigned short)(r >> 16);
}

__device__ inline void split_bf16(float x, unsigned short& hi, unsigned short& lo) {
  unsigned u = __builtin_bit_cast(unsigned, x);
  unsigned r = u + 0x7FFF + ((u >> 16) & 1);  // RNE round to bf16
  hi = (unsigned short)(r >> 16);
  float hf = __builtin_bit_cast(float, r & 0xFFFF0000u);
  float d = x - hf;
  unsigned ud = __builtin_bit_cast(unsigned, d);
  unsigned rd = ud + 0x7FFF + ((ud >> 16) & 1);
  lo = (unsigned short)(rd >> 16);
}

// Fragment-order plane offset (shorts) for logical (row r, k-channel c):
//   off = (r>>4)*2048 + (c>>5)*512 + ((c>>3)&3)*128 + (r&15)*8 + (c&7)
// Lane l = q*16+m of a wave then reads its 16x16x32 A/B frag for (row-tile rt,
// k-chunk kb) as one contiguous v8s at rt*256 + kb*64 + l  (v8s units).
// This matches the layout verified end-to-end in rounds 3-4.

// ---------------- CSR build ----------------

__global__ void hist_kernel(const int* __restrict__ dst, int* __restrict__ deg, int E) {
  int e = blockIdx.x * 256 + threadIdx.x;
  if (e < E) atomicAdd(&deg[dst[e]], 1);
}

__global__ __launch_bounds__(1024) void scan1_kernel(const int* __restrict__ deg,
                                                     int* __restrict__ incl,
                                                     int* __restrict__ blk_sum, int N) {
  __shared__ int lds[1024];
  int t = threadIdx.x;
  int i = blockIdx.x * 1024 + t;
  int v = (i < N) ? deg[i] : 0;
  lds[t] = v;
  __syncthreads();
  for (int off = 1; off < 1024; off <<= 1) {
    int x = (t >= off) ? lds[t - off] : 0;
    __syncthreads();
    lds[t] += x;
    __syncthreads();
  }
  if (i < N) incl[i] = lds[t];
  if (t == 1023) blk_sum[blockIdx.x] = lds[1023];
}

__global__ void scan2_kernel(const int* __restrict__ blk_sum, int* __restrict__ blk_off, int B) {
  __shared__ int lds[256];
  int t = threadIdx.x;
  int v = (t < B) ? blk_sum[t] : 0;
  lds[t] = v;
  __syncthreads();
  for (int off = 1; off < 256; off <<= 1) {
    int x = (t >= off) ? lds[t - off] : 0;
    __syncthreads();
    lds[t] += x;
    __syncthreads();
  }
  blk_off[t] = lds[t] - v;  // exclusive scan of block sums
}

__global__ void rowstart_kernel(const int* __restrict__ incl, const int* __restrict__ deg,
                                const int* __restrict__ blk_off, int* __restrict__ row_start,
                                int N) {
  int i = blockIdx.x * 256 + threadIdx.x;
  if (i < N) row_start[i] = blk_off[i >> 10] + incl[i] - deg[i];
}

__global__ void fill_kernel(const int* __restrict__ src, const int* __restrict__ dst,
                            const int* __restrict__ row_start, int* __restrict__ cursor,
                            int* __restrict__ csr_src, int E) {
  int e = blockIdx.x * 256 + threadIdx.x;
  if (e < E) {
    int d = dst[e];
    int p = atomicAdd(&cursor[d], 1);
    csr_src[row_start[d] + p] = src[e];
  }
}

// ---------------- feature gather -> frag-order hi/lo planes + row-major bf16 ----------------

__global__ void gather_kernel(const float* __restrict__ emb, const int* __restrict__ node_id,
                              unsigned short* __restrict__ hHi, unsigned short* __restrict__ hLo,
                              unsigned short* __restrict__ hRM, int N) {
  int i = blockIdx.x * 256 + threadIdx.x;
  if (i >= N * 32) return;
  int n = i >> 5, q = i & 31;
  float4 v = ((const float4*)emb)[(size_t)node_id[n] * 32 + q];
  float vv[4] = {v.x, v.y, v.z, v.w};
  unsigned short hs[4], ls[4];
#pragma unroll
  for (int k = 0; k < 4; ++k) split_bf16(vv[k], hs[k], ls[k]);
  int c0 = q * 4;
  size_t off = (size_t)(n >> 4) * 2048 + (c0 >> 5) * 512 + (((c0 >> 3) & 3) * 128) +
               ((n & 15) * 8) + (c0 & 7);
  uint2 hp = make_uint2((unsigned)hs[0] | ((unsigned)hs[1] << 16),
                        (unsigned)hs[2] | ((unsigned)hs[3] << 16));
  uint2 lp = make_uint2((unsigned)ls[0] | ((unsigned)ls[1] << 16),
                        (unsigned)ls[2] | ((unsigned)ls[3] << 16));
  *(uint2*)(hHi + off) = hp;
  *(uint2*)(hLo + off) = lp;
  *(uint2*)(hRM + (size_t)n * H + c0) = hp;  // row-major bf16 copy for aggregation
}

// ---------------- weight pre-split: 6x [128x128] fp32 -> frag-order bf16 hi/lo ----------------

__global__ void wsplit_kernel(const float* __restrict__ W0, const float* __restrict__ W1,
                              const float* __restrict__ W2, const float* __restrict__ W3,
                              const float* __restrict__ W4, const float* __restrict__ W5,
                              unsigned short* __restrict__ hi, unsigned short* __restrict__ lo) {
  int i = blockIdx.x * 256 + threadIdx.x;  // 0..24575 (6 planes x 4096 float4-groups)
  int plane = i >> 12;
  int e = (i & 4095) * 4;
  const float* src = plane == 0 ? W0 : plane == 1 ? W1 : plane == 2 ? W2
                   : plane == 3 ? W3 : plane == 4 ? W4 : W5;
  float4 v = *(const float4*)(src + e);
  float vv[4] = {v.x, v.y, v.z, v.w};
  unsigned short hs[4], ls[4];
#pragma unroll
  for (int k = 0; k < 4; ++k) split_bf16(vv[k], hs[k], ls[k]);
  int row = e >> 7, c0 = e & 127;
  size_t off = (size_t)plane * 16384 + (row >> 4) * 2048 + (c0 >> 5) * 512 +
               (((c0 >> 3) & 3) * 128) + ((row & 15) * 8) + (c0 & 7);
  *(uint2*)(&hi[off]) = make_uint2((unsigned)hs[0] | ((unsigned)hs[1] << 16),
                                   (unsigned)hs[2] | ((unsigned)hs[3] << 16));
  *(uint2*)(&lo[off]) = make_uint2((unsigned)ls[0] | ((unsigned)ls[1] << 16),
                                   (unsigned)ls[2] | ((unsigned)ls[3] << 16));
}

// ---------------- mean aggregation (CSR, row-major bf16 gather) -> frag-order planes ----------

__global__ __launch_bounds__(256) void aggregate_kernel(const unsigned short* __restrict__ hRM,
                                                        const int* __restrict__ csr_src,
                                                        const int* __restrict__ row_start,
                                                        const int* __restrict__ deg,
                                                        unsigned short* __restrict__ aggrHi,
                                                        unsigned short* __restrict__ aggrLo,
                                                        int N) {
  int node = blockIdx.x * 4 + (threadIdx.x >> 6);
  if (node >= N) return;
  int lane = threadIdx.x & 63;
  int qe = lane >> 4;  // edge slot 0..3
  int cl = lane & 15;  // channel group: channels cl*8 .. cl*8+7
  const uint4* __restrict__ h16 = (const uint4*)hRM;  // 16 B = 8 bf16; 16 per row

  int start = row_start[node];
  int d = deg[node];

  float acc[8] = {0.f, 0.f, 0.f, 0.f, 0.f, 0.f, 0.f, 0.f};

  auto accum = [&](uint4 u) {
    unsigned uu[4] = {u.x, u.y, u.z, u.w};
#pragma unroll
    for (int j = 0; j < 4; ++j) {
      acc[2 * j] += __builtin_bit_cast(float, uu[j] << 16);
      acc[2 * j + 1] += __builtin_bit_cast(float, uu[j] & 0xFFFF0000u);
    }
  };

  int e = qe;
  for (; e + 4 < d; e += 8) {
    int s0 = csr_src[start + e];
    int s1 = csr_src[start + e + 4];
    uint4 u0 = h16[(size_t)s0 * 16 + cl];
    uint4 u1 = h16[(size_t)s1 * 16 + cl];
    accum(u0);
    accum(u1);
  }
  for (; e < d; e += 4) {
    int s = csr_src[start + e];
    accum(h16[(size_t)s * 16 + cl]);
  }

#pragma unroll
  for (int j = 0; j < 8; ++j) {
    acc[j] += __shfl_xor(acc[j], 16);
    acc[j] += __shfl_xor(acc[j], 32);
  }

  float inv = 1.0f / fmaxf((float)d, 1.0f);
  unsigned short hs[8], ls[8];
#pragma unroll
  for (int j = 0; j < 8; ++j) split_bf16(acc[j] * inv, hs[j], ls[j]);
  // frag-order offset for (node, c0 = cl*8)
  size_t off = (size_t)(node >> 4) * 2048 + (cl >> 2) * 512 + ((cl & 3) * 128) + ((node & 15) * 8);
  if (qe == 0) {
    *(uint4*)(aggrHi + off) = make_uint4((unsigned)hs[0] | ((unsigned)hs[1] << 16),
                                         (unsigned)hs[2] | ((unsigned)hs[3] << 16),
                                         (unsigned)hs[4] | ((unsigned)hs[5] << 16),
                                         (unsigned)hs[6] | ((unsigned)hs[7] << 16));
  } else if (qe == 1) {
    *(uint4*)(aggrLo + off) = make_uint4((unsigned)ls[0] | ((unsigned)ls[1] << 16),
                                         (unsigned)ls[2] | ((unsigned)ls[3] << 16),
                                         (unsigned)ls[4] | ((unsigned)ls[5] << 16),
                                         (unsigned)ls[6] | ((unsigned)ls[7] << 16));
  }
}

// ---------------- split-bf16 MFMA dual-GEMM, LDS-free ----------------
// out = act(aggr@Wl^T + bl + h@Wr^T) via Xhi*Whi + Xlo*Whi + Xhi*Wlo per side.
// All operands are frag-order planes: every A/B frag is ONE contiguous 16 B
// global load (1 KB per wave-load, fully coalesced). No LDS, no barriers.
// 256 threads = 4 waves; wave w owns row-tiles blockIdx*8 + 2w + {0,1}
// (128 rows/block). In-place safe: each wave reads/writes only its own rows,
// ordered by data dependence. hHi/hLo/out planes deliberately NOT restrict
// (they alias across layers).

template <int FINAL>
__global__ __launch_bounds__(256) void gemm_mfma(
    const unsigned short* aggrHi, const unsigned short* aggrLo,
    const unsigned short* hHi, const unsigned short* hLo,
    const unsigned short* __restrict__ wlHi, const unsigned short* __restrict__ wlLo,
    const unsigned short* __restrict__ wrHi, const unsigned short* __restrict__ wrLo,
    const float* __restrict__ bias, float* outF,
    unsigned short* outHi, unsigned short* outLo, unsigned short* outRM, int N) {
  int tid = threadIdx.x;
  int wave = tid >> 6, lane = tid & 63;
  int m = lane & 15, q = lane >> 4;
  int nt = (N + 15) >> 4;
  int rt0 = blockIdx.x * 8 + wave * 2;
  int rt1 = rt0 + 1;
  if (rt0 > nt - 1) rt0 = nt - 1;  // clamped reads; stores guarded by row < N
  if (rt1 > nt - 1) rt1 = nt - 1;

  v4f acc[16];  // [tr*8 + c]
#pragma unroll
  for (int t = 0; t < 16; ++t) acc[t] = (v4f){0.f, 0.f, 0.f, 0.f};

#pragma unroll
  for (int side = 0; side < 2; ++side) {
    const v8s* XH = (const v8s*)(side ? hHi : aggrHi);
    const v8s* XL = (const v8s*)(side ? hLo : aggrLo);
    const v8s* WHp = (const v8s*)(side ? wrHi : wlHi);
    const v8s* WLp = (const v8s*)(side ? wrLo : wlLo);
#pragma unroll
    for (int kb = 0; kb < 4; ++kb) {
      int ib = kb * 64 + lane;
      v8s ah0 = XH[(size_t)rt0 * 256 + ib];
      v8s al0 = XL[(size_t)rt0 * 256 + ib];
      v8s ah1 = XH[(size_t)rt1 * 256 + ib];
      v8s al1 = XL[(size_t)rt1 * 256 + ib];
#pragma unroll
      for (int c = 0; c < 8; ++c) {
        v8s bh = WHp[c * 256 + ib];
        v8s bl = WLp[c * 256 + ib];
        acc[c] = __builtin_amdgcn_mfma_f32_16x16x32_bf16(ah0, bh, acc[c], 0, 0, 0);
        acc[c] = __builtin_amdgcn_mfma_f32_16x16x32_bf16(al0, bh, acc[c], 0, 0, 0);
        acc[c] = __builtin_amdgcn_mfma_f32_16x16x32_bf16(ah0, bl, acc[c], 0, 0, 0);
        acc[8 + c] = __builtin_amdgcn_mfma_f32_16x16x32_bf16(ah1, bh, acc[8 + c], 0, 0, 0);
        acc[8 + c] = __builtin_amdgcn_mfma_f32_16x16x32_bf16(al1, bh, acc[8 + c], 0, 0, 0);
        acc[8 + c] = __builtin_amdgcn_mfma_f32_16x16x32_bf16(ah1, bl, acc[8 + c], 0, 0, 0);
      }
    }
  }

  // --- epilogue: bias (+relu); FINAL: fp32 row-major; else frag hi/lo + row-major bf16 ---
  float bv[8];
#pragma unroll
  for (int c = 0; c < 8; ++c) bv[c] = bias[c * 16 + m];
#pragma unroll
  for (int tr = 0; tr < 2; ++tr) {
#pragma unroll
    for (int c = 0; c < 8; ++c) {
      v4f a = acc[tr * 8 + c];
#pragma unroll
      for (int i = 0; i < 4; ++i) {
        int row = blockIdx.x * 128 + wave * 32 + tr * 16 + q * 4 + i;
        if (row < N) {
          float v = a[i] + bv[c];
          if (FINAL) {
            outF[(size_t)row * H + c * 16 + m] = v;
          } else {
            v = fmaxf(v, 0.f);
            unsigned short hs, ls;
            split_bf16(v, hs, ls);
            size_t fo = (size_t)(row >> 4) * 2048 + (c >> 1) * 512 +
                        ((((c & 1) << 1) | (m >> 3)) * 128) + ((row & 15) * 8) + (m & 7);
            outHi[fo] = hs;
            outLo[fo] = ls;
            outRM[(size_t)row * H + c * 16 + m] = hs;
          }
        }
      }
    }
  }
}

// ---------------- launch ----------------

extern "C" void kernel_launch(void* const* d_in, const int* in_sizes, int n_in,
                              void* d_out, int out_size, void* d_ws, size_t ws_size,
                              hipStream_t stream) {
  const int* node_id = (const int*)d_in[0];
  const int* edge_index = (const int*)d_in[1];
  const float* emb = (const float*)d_in[2];
  const float* W1l = (const float*)d_in[3];
  const float* b1l = (const float*)d_in[4];
  const float* W1r = (const float*)d_in[5];
  const float* W2l = (const float*)d_in[6];
  const float* b2l = (const float*)d_in[7];
  const float* W2r = (const float*)d_in[8];
  const float* W3l = (const float*)d_in[9];
  const float* b3l = (const float*)d_in[10];
  const float* W3r = (const float*)d_in[11];

  int N = in_sizes[0];
  int E = in_sizes[1] / 2;
  const int* src = edge_index;
  const int* dst = edge_index + E;

  char* w = (char*)d_ws;
  auto alloc = [&](size_t bytes) {
    void* p = (void*)w;
    w += (bytes + 255) & ~(size_t)255;
    return p;
  };
  int* deg = (int*)alloc((size_t)N * 4);
  int* cursor = (int*)alloc((size_t)N * 4);
  int* row_start = (int*)alloc((size_t)N * 4);
  int* incl = (int*)alloc((size_t)N * 4);
  int* blk_sum = (int*)alloc(1024);
  int* blk_off = (int*)alloc(1024);
  int* csr_src = (int*)alloc((size_t)E * 4);
  size_t nt = ((size_t)N + 15) >> 4;
  unsigned short* hHi = (unsigned short*)alloc(nt * 2048 * 2);
  unsigned short* hLo = (unsigned short*)alloc(nt * 2048 * 2);
  unsigned short* hRM = (unsigned short*)alloc((size_t)N * H * 2);
  unsigned short* aggrHi = (unsigned short*)alloc(nt * 2048 * 2);
  unsigned short* aggrLo = (unsigned short*)alloc(nt * 2048 * 2);
  unsigned short* whi = (unsigned short*)alloc(6 * 16384 * 2);
  unsigned short* wlo = (unsigned short*)alloc(6 * 16384 * 2);

  hipMemsetAsync(deg, 0, (size_t)N * 4, stream);
  hipMemsetAsync(cursor, 0, (size_t)N * 4, stream);

  hist_kernel<<<(E + 255) / 256, 256, 0, stream>>>(dst, deg, E);
  int SB = (N + 1023) / 1024;
  scan1_kernel<<<SB, 1024, 0, stream>>>(deg, incl, blk_sum, N);
  scan2_kernel<<<1, 256, 0, stream>>>(blk_sum, blk_off, SB);
  rowstart_kernel<<<(N + 255) / 256, 256, 0, stream>>>(incl, deg, blk_off, row_start, N);
  fill_kernel<<<(E + 255) / 256, 256, 0, stream>>>(src, dst, row_start, cursor, csr_src, E);

  gather_kernel<<<(N * 32 + 255) / 256, 256, 0, stream>>>(emb, node_id, hHi, hLo, hRM, N);
  // planes order: [W1l, W1r, W2l, W2r, W3l, W3r]
  wsplit_kernel<<<96, 256, 0, stream>>>(W1l, W1r, W2l, W2r, W3l, W3r, whi, wlo);

  int gag = (N + 3) / 4;
  int ggm = (N + 127) / 128;

  aggregate_kernel<<<gag, 256, 0, stream>>>(hRM, csr_src, row_start, deg, aggrHi, aggrLo, N);
  gemm_mfma<0><<<ggm, 256, 0, stream>>>(aggrHi, aggrLo, hHi, hLo,
                                        whi + 0 * 16384, wlo + 0 * 16384,
                                        whi + 1 * 16384, wlo + 1 * 16384,
                                        b1l, nullptr, hHi, hLo, hRM, N);

  aggregate_kernel<<<gag, 256, 0, stream>>>(hRM, csr_src, row_start, deg, aggrHi, aggrLo, N);
  gemm_mfma<0><<<ggm, 256, 0, stream>>>(aggrHi, aggrLo, hHi, hLo,
                                        whi + 2 * 16384, wlo + 2 * 16384,
                                        whi + 3 * 16384, wlo + 3 * 16384,
                                        b2l, nullptr, hHi, hLo, hRM, N);

  aggregate_kernel<<<gag, 256, 0, stream>>>(hRM, csr_src, row_start, deg, aggrHi, aggrLo, N);
  gemm_mfma<1><<<ggm, 256, 0, stream>>>(aggrHi, aggrLo, hHi, hLo,
                                        whi + 4 * 16384, wlo + 4 * 16384,
                                        whi + 5 * 16384, wlo + 5 * 16384,
                                        b3l, (float*)d_out, nullptr, nullptr, nullptr, N);
}

// Round 7
// 493.930 us; speedup vs baseline: 1.0822x; 1.0822x over previous
//
#include <hip/hip_runtime.h>

#define H 128

typedef float v4f __attribute__((ext_vector_type(4)));
typedef short v8s __attribute__((ext_vector_type(8)));

// ---------------- bf16 helpers ----------------

__device__ inline unsigned short bf16_rne(float x) {
  unsigned u = __builtin_bit_cast(unsigned, x);
  unsigned r = u + 0x7FFF + ((u >> 16) & 1);
  return (unsigned short)(r >> 16);
}

__device__ inline void split_bf16(float x, unsigned short& hi, unsigned short& lo) {
  unsigned u = __builtin_bit_cast(unsigned, x);
  unsigned r = u + 0x7FFF + ((u >> 16) & 1);  // RNE round to bf16
  hi = (unsigned short)(r >> 16);
  float hf = __builtin_bit_cast(float, r & 0xFFFF0000u);
  float d = x - hf;
  unsigned ud = __builtin_bit_cast(unsigned, d);
  unsigned rd = ud + 0x7FFF + ((ud >> 16) & 1);
  lo = (unsigned short)(rd >> 16);
}

// Fragment-order plane offset (shorts) for logical (row r, k-channel c):
//   off = (r>>4)*2048 + (c>>5)*512 + ((c>>3)&3)*128 + (r&15)*8 + (c&7)
// Lane l = q*16+m of a wave reads its 16x16x32 A/B frag for (row-tile rt,
// k-chunk kb) as one contiguous v8s at rt*256 + kb*64 + l  (v8s units).

// ---------------- CSR build ----------------

__global__ void hist_kernel(const int* __restrict__ dst, int* __restrict__ deg, int E) {
  int e = blockIdx.x * 256 + threadIdx.x;
  if (e < E) atomicAdd(&deg[dst[e]], 1);
}

__global__ __launch_bounds__(1024) void scan1_kernel(const int* __restrict__ deg,
                                                     int* __restrict__ incl,
                                                     int* __restrict__ blk_sum, int N) {
  __shared__ int lds[1024];
  int t = threadIdx.x;
  int i = blockIdx.x * 1024 + t;
  int v = (i < N) ? deg[i] : 0;
  lds[t] = v;
  __syncthreads();
  for (int off = 1; off < 1024; off <<= 1) {
    int x = (t >= off) ? lds[t - off] : 0;
    __syncthreads();
    lds[t] += x;
    __syncthreads();
  }
  if (i < N) incl[i] = lds[t];
  if (t == 1023) blk_sum[blockIdx.x] = lds[1023];
}

__global__ void scan2_kernel(const int* __restrict__ blk_sum, int* __restrict__ blk_off, int B) {
  __shared__ int lds[256];
  int t = threadIdx.x;
  int v = (t < B) ? blk_sum[t] : 0;
  lds[t] = v;
  __syncthreads();
  for (int off = 1; off < 256; off <<= 1) {
    int x = (t >= off) ? lds[t - off] : 0;
    __syncthreads();
    lds[t] += x;
    __syncthreads();
  }
  blk_off[t] = lds[t] - v;  // exclusive scan of block sums
}

__global__ void rowstart_kernel(const int* __restrict__ incl, const int* __restrict__ deg,
                                const int* __restrict__ blk_off, int* __restrict__ row_start,
                                int N) {
  int i = blockIdx.x * 256 + threadIdx.x;
  if (i < N) row_start[i] = blk_off[i >> 10] + incl[i] - deg[i];
}

__global__ void fill_kernel(const int* __restrict__ src, const int* __restrict__ dst,
                            const int* __restrict__ row_start, int* __restrict__ cursor,
                            int* __restrict__ csr_src, int E) {
  int e = blockIdx.x * 256 + threadIdx.x;
  if (e < E) {
    int d = dst[e];
    int p = atomicAdd(&cursor[d], 1);
    csr_src[row_start[d] + p] = src[e];
  }
}

// ---------------- feature gather -> frag-order hi/lo planes + row-major bf16 ----------------

__global__ void gather_kernel(const float* __restrict__ emb, const int* __restrict__ node_id,
                              unsigned short* __restrict__ hHi, unsigned short* __restrict__ hLo,
                              unsigned short* __restrict__ hRM, int N) {
  int i = blockIdx.x * 256 + threadIdx.x;
  if (i >= N * 32) return;
  int n = i >> 5, q = i & 31;
  float4 v = ((const float4*)emb)[(size_t)node_id[n] * 32 + q];
  float vv[4] = {v.x, v.y, v.z, v.w};
  unsigned short hs[4], ls[4];
#pragma unroll
  for (int k = 0; k < 4; ++k) split_bf16(vv[k], hs[k], ls[k]);
  int c0 = q * 4;
  size_t off = (size_t)(n >> 4) * 2048 + (c0 >> 5) * 512 + (((c0 >> 3) & 3) * 128) +
               ((n & 15) * 8) + (c0 & 7);
  uint2 hp = make_uint2((unsigned)hs[0] | ((unsigned)hs[1] << 16),
                        (unsigned)hs[2] | ((unsigned)hs[3] << 16));
  uint2 lp = make_uint2((unsigned)ls[0] | ((unsigned)ls[1] << 16),
                        (unsigned)ls[2] | ((unsigned)ls[3] << 16));
  *(uint2*)(hHi + off) = hp;
  *(uint2*)(hLo + off) = lp;
  *(uint2*)(hRM + (size_t)n * H + c0) = hp;  // row-major bf16 copy for aggregation
}

// ---------------- weight pre-split: 6x [128x128] fp32 -> frag-order bf16 hi/lo ----------------

__global__ void wsplit_kernel(const float* __restrict__ W0, const float* __restrict__ W1,
                              const float* __restrict__ W2, const float* __restrict__ W3,
                              const float* __restrict__ W4, const float* __restrict__ W5,
                              unsigned short* __restrict__ hi, unsigned short* __restrict__ lo) {
  int i = blockIdx.x * 256 + threadIdx.x;  // 0..24575 (6 planes x 4096 float4-groups)
  int plane = i >> 12;
  int e = (i & 4095) * 4;
  const float* src = plane == 0 ? W0 : plane == 1 ? W1 : plane == 2 ? W2
                   : plane == 3 ? W3 : plane == 4 ? W4 : W5;
  float4 v = *(const float4*)(src + e);
  float vv[4] = {v.x, v.y, v.z, v.w};
  unsigned short hs[4], ls[4];
#pragma unroll
  for (int k = 0; k < 4; ++k) split_bf16(vv[k], hs[k], ls[k]);
  int row = e >> 7, c0 = e & 127;
  size_t off = (size_t)plane * 16384 + (row >> 4) * 2048 + (c0 >> 5) * 512 +
               (((c0 >> 3) & 3) * 128) + ((row & 15) * 8) + (c0 & 7);
  *(uint2*)(&hi[off]) = make_uint2((unsigned)hs[0] | ((unsigned)hs[1] << 16),
                                   (unsigned)hs[2] | ((unsigned)hs[3] << 16));
  *(uint2*)(&lo[off]) = make_uint2((unsigned)ls[0] | ((unsigned)ls[1] << 16),
                                   (unsigned)ls[2] | ((unsigned)ls[3] << 16));
}

// ---------------- mean aggregation (CSR, row-major bf16 gather) -> frag-order planes ----------

__global__ __launch_bounds__(256) void aggregate_kernel(const unsigned short* __restrict__ hRM,
                                                        const int* __restrict__ csr_src,
                                                        const int* __restrict__ row_start,
                                                        const int* __restrict__ deg,
                                                        unsigned short* __restrict__ aggrHi,
                                                        unsigned short* __restrict__ aggrLo,
                                                        int N) {
  int node = blockIdx.x * 4 + (threadIdx.x >> 6);
  if (node >= N) return;
  int lane = threadIdx.x & 63;
  int qe = lane >> 4;  // edge slot 0..3
  int cl = lane & 15;  // channel group: channels cl*8 .. cl*8+7
  const uint4* __restrict__ h16 = (const uint4*)hRM;  // 16 B = 8 bf16; 16 per row

  int start = row_start[node];
  int d = deg[node];

  float acc[8] = {0.f, 0.f, 0.f, 0.f, 0.f, 0.f, 0.f, 0.f};

  auto accum = [&](uint4 u) {
    unsigned uu[4] = {u.x, u.y, u.z, u.w};
#pragma unroll
    for (int j = 0; j < 4; ++j) {
      acc[2 * j] += __builtin_bit_cast(float, uu[j] << 16);
      acc[2 * j + 1] += __builtin_bit_cast(float, uu[j] & 0xFFFF0000u);
    }
  };

  int e = qe;
  for (; e + 4 < d; e += 8) {
    int s0 = csr_src[start + e];
    int s1 = csr_src[start + e + 4];
    uint4 u0 = h16[(size_t)s0 * 16 + cl];
    uint4 u1 = h16[(size_t)s1 * 16 + cl];
    accum(u0);
    accum(u1);
  }
  for (; e < d; e += 4) {
    int s = csr_src[start + e];
    accum(h16[(size_t)s * 16 + cl]);
  }

#pragma unroll
  for (int j = 0; j < 8; ++j) {
    acc[j] += __shfl_xor(acc[j], 16);
    acc[j] += __shfl_xor(acc[j], 32);
  }

  float inv = 1.0f / fmaxf((float)d, 1.0f);
  unsigned short hs[8], ls[8];
#pragma unroll
  for (int j = 0; j < 8; ++j) split_bf16(acc[j] * inv, hs[j], ls[j]);
  // frag-order offset for (node, c0 = cl*8)
  size_t off = (size_t)(node >> 4) * 2048 + (cl >> 2) * 512 + ((cl & 3) * 128) + ((node & 15) * 8);
  if (qe == 0) {
    *(uint4*)(aggrHi + off) = make_uint4((unsigned)hs[0] | ((unsigned)hs[1] << 16),
                                         (unsigned)hs[2] | ((unsigned)hs[3] << 16),
                                         (unsigned)hs[4] | ((unsigned)hs[5] << 16),
                                         (unsigned)hs[6] | ((unsigned)hs[7] << 16));
  } else if (qe == 1) {
    *(uint4*)(aggrLo + off) = make_uint4((unsigned)ls[0] | ((unsigned)ls[1] << 16),
                                         (unsigned)ls[2] | ((unsigned)ls[3] << 16),
                                         (unsigned)ls[4] | ((unsigned)ls[5] << 16),
                                         (unsigned)ls[6] | ((unsigned)ls[7] << 16));
  }
}

// ---------------- split-bf16 MFMA dual-GEMM: A from global, W shared via LDS ----------------
// out = act(aggr@Wl^T + bl + h@Wr^T) via Xhi*Whi + Xlo*Whi + Xhi*Wlo per side.
// A frags: direct contiguous 16 B global loads from frag-order planes (each A
// row streamed exactly once). W: staged into LDS ONCE per side (linear 64 KB
// copy, coalesced uint4 -> ds_write_b128), then every B frag is a ds_read_b128
// shared by all 4 waves -- this removes R6's 128 KB/wave private W re-fetch.
// 256 threads = 4 waves; wave w owns row-tiles blockIdx*8 + 2w + {0,1}.
// In-place safe: each wave reads/writes only its own rows (data-dependence
// ordered). h/out planes deliberately NOT restrict (they alias across layers).

template <int FINAL>
__global__ __launch_bounds__(256) void gemm_mfma(
    const unsigned short* aggrHi, const unsigned short* aggrLo,
    const unsigned short* hHi, const unsigned short* hLo,
    const unsigned short* __restrict__ wlHi, const unsigned short* __restrict__ wlLo,
    const unsigned short* __restrict__ wrHi, const unsigned short* __restrict__ wrLo,
    const float* __restrict__ bias, float* outF,
    unsigned short* outHi, unsigned short* outLo, unsigned short* outRM, int N) {
  __shared__ __align__(16) unsigned short WhS[16384];  // 32 KB: one W hi plane, frag order
  __shared__ __align__(16) unsigned short WlS[16384];  // 32 KB: one W lo plane, frag order

  int tid = threadIdx.x;
  int wave = tid >> 6, lane = tid & 63;
  int m = lane & 15, q = lane >> 4;
  int nt = (N + 15) >> 4;
  int rt0 = blockIdx.x * 8 + wave * 2;
  int rt1 = rt0 + 1;
  if (rt0 > nt - 1) rt0 = nt - 1;  // clamped reads; stores guarded by row < N
  if (rt1 > nt - 1) rt1 = nt - 1;

  v4f acc[16];  // [tr*8 + c]
#pragma unroll
  for (int t = 0; t < 16; ++t) acc[t] = (v4f){0.f, 0.f, 0.f, 0.f};

  for (int side = 0; side < 2; ++side) {
    const v8s* XH = (const v8s*)(side ? hHi : aggrHi);
    const v8s* XL = (const v8s*)(side ? hLo : aggrLo);
    const uint4* WHg = (const uint4*)(side ? wrHi : wlHi);
    const uint4* WLg = (const uint4*)(side ? wrLo : wlLo);

    __syncthreads();  // previous side's LDS reads complete before overwrite
#pragma unroll
    for (int j = 0; j < 8; ++j) {  // 2048 uint4 per plane, linear coalesced copy
      ((uint4*)WhS)[j * 256 + tid] = WHg[j * 256 + tid];
      ((uint4*)WlS)[j * 256 + tid] = WLg[j * 256 + tid];
    }
    __syncthreads();

    const v8s* WhF = (const v8s*)WhS;
    const v8s* WlF = (const v8s*)WlS;
#pragma unroll
    for (int kb = 0; kb < 4; ++kb) {
      int ib = kb * 64 + lane;
      v8s ah0 = XH[(size_t)rt0 * 256 + ib];
      v8s al0 = XL[(size_t)rt0 * 256 + ib];
      v8s ah1 = XH[(size_t)rt1 * 256 + ib];
      v8s al1 = XL[(size_t)rt1 * 256 + ib];
#pragma unroll
      for (int c = 0; c < 8; ++c) {
        v8s bh = WhF[c * 256 + ib];
        v8s bl = WlF[c * 256 + ib];
        acc[c] = __builtin_amdgcn_mfma_f32_16x16x32_bf16(ah0, bh, acc[c], 0, 0, 0);
        acc[c] = __builtin_amdgcn_mfma_f32_16x16x32_bf16(al0, bh, acc[c], 0, 0, 0);
        acc[c] = __builtin_amdgcn_mfma_f32_16x16x32_bf16(ah0, bl, acc[c], 0, 0, 0);
        acc[8 + c] = __builtin_amdgcn_mfma_f32_16x16x32_bf16(ah1, bh, acc[8 + c], 0, 0, 0);
        acc[8 + c] = __builtin_amdgcn_mfma_f32_16x16x32_bf16(al1, bh, acc[8 + c], 0, 0, 0);
        acc[8 + c] = __builtin_amdgcn_mfma_f32_16x16x32_bf16(ah1, bl, acc[8 + c], 0, 0, 0);
      }
    }
  }

  // --- epilogue: bias (+relu); FINAL: fp32 row-major; else frag hi/lo + row-major bf16 ---
  float bv[8];
#pragma unroll
  for (int c = 0; c < 8; ++c) bv[c] = bias[c * 16 + m];
#pragma unroll
  for (int tr = 0; tr < 2; ++tr) {
#pragma unroll
    for (int c = 0; c < 8; ++c) {
      v4f a = acc[tr * 8 + c];
#pragma unroll
      for (int i = 0; i < 4; ++i) {
        int row = blockIdx.x * 128 + wave * 32 + tr * 16 + q * 4 + i;
        if (row < N) {
          float v = a[i] + bv[c];
          if (FINAL) {
            outF[(size_t)row * H + c * 16 + m] = v;
          } else {
            v = fmaxf(v, 0.f);
            unsigned short hs, ls;
            split_bf16(v, hs, ls);
            size_t fo = (size_t)(row >> 4) * 2048 + (c >> 1) * 512 +
                        ((((c & 1) << 1) | (m >> 3)) * 128) + ((row & 15) * 8) + (m & 7);
            outHi[fo] = hs;
            outLo[fo] = ls;
            outRM[(size_t)row * H + c * 16 + m] = hs;
          }
        }
      }
    }
  }
}

// ---------------- launch ----------------

extern "C" void kernel_launch(void* const* d_in, const int* in_sizes, int n_in,
                              void* d_out, int out_size, void* d_ws, size_t ws_size,
                              hipStream_t stream) {
  const int* node_id = (const int*)d_in[0];
  const int* edge_index = (const int*)d_in[1];
  const float* emb = (const float*)d_in[2];
  const float* W1l = (const float*)d_in[3];
  const float* b1l = (const float*)d_in[4];
  const float* W1r = (const float*)d_in[5];
  const float* W2l = (const float*)d_in[6];
  const float* b2l = (const float*)d_in[7];
  const float* W2r = (const float*)d_in[8];
  const float* W3l = (const float*)d_in[9];
  const float* b3l = (const float*)d_in[10];
  const float* W3r = (const float*)d_in[11];

  int N = in_sizes[0];
  int E = in_sizes[1] / 2;
  const int* src = edge_index;
  const int* dst = edge_index + E;

  char* w = (char*)d_ws;
  auto alloc = [&](size_t bytes) {
    void* p = (void*)w;
    w += (bytes + 255) & ~(size_t)255;
    return p;
  };
  int* deg = (int*)alloc((size_t)N * 4);
  int* cursor = (int*)alloc((size_t)N * 4);
  int* row_start = (int*)alloc((size_t)N * 4);
  int* incl = (int*)alloc((size_t)N * 4);
  int* blk_sum = (int*)alloc(1024);
  int* blk_off = (int*)alloc(1024);
  int* csr_src = (int*)alloc((size_t)E * 4);
  size_t nt = ((size_t)N + 15) >> 4;
  unsigned short* hHi = (unsigned short*)alloc(nt * 2048 * 2);
  unsigned short* hLo = (unsigned short*)alloc(nt * 2048 * 2);
  unsigned short* hRM = (unsigned short*)alloc((size_t)N * H * 2);
  unsigned short* aggrHi = (unsigned short*)alloc(nt * 2048 * 2);
  unsigned short* aggrLo = (unsigned short*)alloc(nt * 2048 * 2);
  unsigned short* whi = (unsigned short*)alloc(6 * 16384 * 2);
  unsigned short* wlo = (unsigned short*)alloc(6 * 16384 * 2);

  hipMemsetAsync(deg, 0, (size_t)N * 4, stream);
  hipMemsetAsync(cursor, 0, (size_t)N * 4, stream);

  hist_kernel<<<(E + 255) / 256, 256, 0, stream>>>(dst, deg, E);
  int SB = (N + 1023) / 1024;
  scan1_kernel<<<SB, 1024, 0, stream>>>(deg, incl, blk_sum, N);
  scan2_kernel<<<1, 256, 0, stream>>>(blk_sum, blk_off, SB);
  rowstart_kernel<<<(N + 255) / 256, 256, 0, stream>>>(incl, deg, blk_off, row_start, N);
  fill_kernel<<<(E + 255) / 256, 256, 0, stream>>>(src, dst, row_start, cursor, csr_src, E);

  gather_kernel<<<(N * 32 + 255) / 256, 256, 0, stream>>>(emb, node_id, hHi, hLo, hRM, N);
  // planes order: [W1l, W1r, W2l, W2r, W3l, W3r]
  wsplit_kernel<<<96, 256, 0, stream>>>(W1l, W1r, W2l, W2r, W3l, W3r, whi, wlo);

  int gag = (N + 3) / 4;
  int ggm = (N + 127) / 128;

  aggregate_kernel<<<gag, 256, 0, stream>>>(hRM, csr_src, row_start, deg, aggrHi, aggrLo, N);
  gemm_mfma<0><<<ggm, 256, 0, stream>>>(aggrHi, aggrLo, hHi, hLo,
                                        whi + 0 * 16384, wlo + 0 * 16384,
                                        whi + 1 * 16384, wlo + 1 * 16384,
                                        b1l, nullptr, hHi, hLo, hRM, N);

  aggregate_kernel<<<gag, 256, 0, stream>>>(hRM, csr_src, row_start, deg, aggrHi, aggrLo, N);
  gemm_mfma<0><<<ggm, 256, 0, stream>>>(aggrHi, aggrLo, hHi, hLo,
                                        whi + 2 * 16384, wlo + 2 * 16384,
                                        whi + 3 * 16384, wlo + 3 * 16384,
                                        b2l, nullptr, hHi, hLo, hRM, N);

  aggregate_kernel<<<gag, 256, 0, stream>>>(hRM, csr_src, row_start, deg, aggrHi, aggrLo, N);
  gemm_mfma<1><<<ggm, 256, 0, stream>>>(aggrHi, aggrLo, hHi, hLo,
                                        whi + 4 * 16384, wlo + 4 * 16384,
                                        whi + 5 * 16384, wlo + 5 * 16384,
                                        b3l, (float*)d_out, nullptr, nullptr, nullptr, N);
}